// Round 2
// baseline (310.480 us; speedup 1.0000x reference)
//
#include <hip/hip_runtime.h>
#include <stdint.h>

#define BDIM    512                   // 8 waves per batch
#define NROWS   32
#define CDIM    1024
#define NSTEPS  31
#define BATCH   512

// One 512-thread block (8 waves) per batch. ALL alive rows live in REGISTERS:
// wave w owns 4 "banks" k=0..3 holding slots s = w + 8k (strided ownership);
// lane holds elements [lane*16..+15]. Merged row overwrites slot sb's bank
// and D-row. The OTHER dead slot is idx[a] normally but idx[0] when a==1
// (reference quirk) — kill THAT bank.
//
// INCREMENTAL ARGMIN, 2 barriers/step:
//   Phase A: reduce <=16 per-wave partials from LDS (redundant on every
//     thread) -> (a,bbj). Conv partials (owner waves) + bookkeeping
//     (next idx/pos buffers) + scan of OLD surviving pairs in NEXT-step
//     numbering (positions derived arithmetically from old pos + (a,bbj),
//     no race) -> per-wave partial 0..7.  B2.
//   Phase B: finalize m; dist(m, live banks) in fp64; 7-shuffle multi-value
//     reduce (lanes 0..3 hold the 4 sums); write D; fold own new-pair
//     candidates (flat' = 0*n'+j' < any old flat' — matches reference
//     flat-index order) -> per-wave partial 8..15.  B3.
// Next step's argmin = 16-entry LDS scan. fp64 sum reassociation only
// (decisions/output bit-identical). No global reads after init.
__device__ __forceinline__ int mapPos(int j, int n, int a, int bbj, int deadPos) {
    // old logical pos -> next-step logical pos (127 = dead)
    if (j >= n)       return 127;     // already dead
    if (j == bbj)     return 0;       // merged row
    if (j == deadPos) return 127;     // dies this step
    if (j == 0)       return a - 1;   // only reached when a>=2
    if (j == 1)       return bbj - 1; // only reached when bbj>=2
    return j - 1;
}

__device__ __forceinline__ double reduce4(double a0, double a1, double a2, double a3, int lane) {
    // Joint wave-sum of 4 fp64 values; lane l ends holding S_{l&3}.
    double t, r, b01, b23, c;
    t = (lane & 1) ? a0 : a1; r = (lane & 1) ? a1 : a0; b01 = r + __shfl_xor(t, 1);
    t = (lane & 1) ? a2 : a3; r = (lane & 1) ? a3 : a2; b23 = r + __shfl_xor(t, 1);
    t = (lane & 2) ? b01 : b23; r = (lane & 2) ? b23 : b01; c = r + __shfl_xor(t, 2);
    c += __shfl_xor(c, 4); c += __shfl_xor(c, 8); c += __shfl_xor(c, 16); c += __shfl_xor(c, 32);
    return c;
}

__global__ __launch_bounds__(BDIM, 4)
void merge_tree_kernel(const float* __restrict__ xin,  // B*32*1024 fp32
                       const float* __restrict__ wz,   // 6 fp32 (1,2,3)
                       const float* __restrict__ bz,   // 1 fp32
                       float* __restrict__ out)        // B*1024 fp32
{
    const int b    = blockIdx.x;
    const int tid  = threadIdx.x;
    const int lane = tid & 63;
    const int wid  = tid >> 6;        // 0..7

    const float* xb = xin + (size_t)b * NROWS * CDIM;

    __shared__ double D[NROWS][NROWS + 1];   // slot-indexed d2 (8448 B)
    __shared__ float  mA[16 * 64];           // conv partial (ch0), [e][lane]
    __shared__ float  mB[16 * 64];           // conv partial (ch1), [e][lane]
    __shared__ int    idxbuf[2][NROWS];      // logical pos -> slot
    __shared__ int    posbuf[2][NROWS];      // slot -> logical pos, 127 = dead
    __shared__ int    bankSlot[32];          // bank (wid*4+k) -> slot, -1 dead
    __shared__ double wpK[2][16];            // argmin partial keys (dbl-buffered)
    __shared__ int    wpP[2][16];            // argmin partial flat

    const float w00 = wz[0], w01 = wz[1], w02 = wz[2];
    const float w10 = wz[3], w11 = wz[4], w12 = wz[5];
    const float cb  = bz[0];

    float R[4][16];                   // 4 owned rows (64 VGPRs)
    float m[16];                      // streamed / merged row
    float nxt[16];                    // init prefetch buffer

    if (tid < NROWS) {
        idxbuf[0][tid] = tid;
        posbuf[0][tid] = tid;
        bankSlot[tid] = (tid >> 2) + ((tid & 3) << 3);   // strided ownership
    }
    if (tid < 16) {
        wpK[0][tid] = 1e300; wpK[1][tid] = 1e300;
        wpP[0][tid] = 0x7fffffff; wpP[1][tid] = 0x7fffffff;
    }

    // ---------- single-pass init: stream row i, owner captures, dist vs s<i ----------
    {
        const float4* src = (const float4*)xb;    // row 0
        #pragma unroll
        for (int q = 0; q < 4; q++) {
            float4 t = src[lane * 4 + q];
            m[4*q] = t.x; m[4*q+1] = t.y; m[4*q+2] = t.z; m[4*q+3] = t.w;
        }
    }
    #pragma unroll 1
    for (int i = 0; i < NROWS; i++) {
        if (i < NROWS - 1) {                      // prefetch row i+1
            const float4* src = (const float4*)(xb + (size_t)(i + 1) * CDIM);
            #pragma unroll
            for (int q = 0; q < 4; q++) {
                float4 t = src[lane * 4 + q];
                nxt[4*q] = t.x; nxt[4*q+1] = t.y; nxt[4*q+2] = t.z; nxt[4*q+3] = t.w;
            }
        }
        double accv[4]; int sl0, sl1, sl2, sl3;
        #pragma unroll
        for (int k = 0; k < 4; k++) {
            const int s = wid + (k << 3);         // strided slot, wave-uniform
            double acc = 0.0;
            if (s < i) {                          // wave-uniform
                #pragma unroll
                for (int e = 0; e < 16; e++) {
                    float d = m[e] - R[k][e];
                    acc += (double)d * (double)d;
                }
            } else if (s == i) {                  // owner captures streamed row
                #pragma unroll
                for (int e = 0; e < 16; e++) R[k][e] = m[e];
            }
            accv[k] = acc;
        }
        sl0 = ((wid + 0)  < i) ? (wid + 0)  : -1;
        sl1 = ((wid + 8)  < i) ? (wid + 8)  : -1;
        sl2 = ((wid + 16) < i) ? (wid + 16) : -1;
        sl3 = ((wid + 24) < i) ? (wid + 24) : -1;
        double c = reduce4(accv[0], accv[1], accv[2], accv[3], lane);
        int s_lane = sl0;
        s_lane = ((lane & 3) == 1) ? sl1 : s_lane;
        s_lane = ((lane & 3) == 2) ? sl2 : s_lane;
        s_lane = ((lane & 3) == 3) ? sl3 : s_lane;
        if (lane < 4 && s_lane >= 0) { D[i][s_lane] = c; D[s_lane][i] = c; }

        if (i < NROWS - 1) {
            #pragma unroll
            for (int e = 0; e < 16; e++) m[e] = nxt[e];
        }
    }
    __syncthreads();

    // ---------- pre-loop full argmin scan (step-0 numbering, posb identity) ----------
    {
        double bk = 1e300; int bp = 0x7fffffff;
        #pragma unroll
        for (int r = 0; r < 2; r++) {
            const int flat = r * BDIM + tid;
            const int s = flat >> 5, t = flat & 31;
            if (t > s) {
                double d2 = D[s][t];
                int fi = s * NROWS + t;
                if (d2 < bk || (d2 == bk && fi < bp)) { bk = d2; bp = fi; }
            }
        }
        #pragma unroll
        for (int off = 1; off < 64; off <<= 1) {
            double ov = __shfl_xor(bk, off); int op = __shfl_xor(bp, off);
            if (ov < bk || (ov == bk && op < bp)) { bk = ov; bp = op; }
        }
        if (lane == 0) { wpK[0][wid] = bk; wpP[0][wid] = bp; }
    }
    __syncthreads();

    // ---------- main merge loop: 2 barriers/step ----------
    int p = 0;
    #pragma unroll 1
    for (int step = 0; step < NSTEPS; step++) {
        const int n  = NROWS - step;
        const int n1 = n - 1;                              // next-step n'
        int* idx  = idxbuf[p];
        int* nidx = idxbuf[p ^ 1];
        int* pos  = posbuf[p];
        int* npos = posbuf[p ^ 1];
        const uint32_t M = 0xFFFFFFFFu / (uint32_t)n + 1u; // exact for flat<2^27

        // ===================== Phase A =====================
        // --- final reduce of 16 partials, redundant on every thread ---
        double bk = wpK[p][0]; int bp = wpP[p][0];
        #pragma unroll
        for (int w = 1; w < 16; w++) {
            double ov = wpK[p][w]; int op = wpP[p][w];
            if (ov < bk || (ov == bk && op < bp)) { bk = ov; bp = op; }
        }
        const int a   = (int)__umulhi((uint32_t)bp, M);
        const int bbj = bp - a * n;
        const int sa  = idx[a], sb = idx[bbj];
        const int deadSlot = (a == 1) ? idx[0] : sa;
        const int deadPos  = (a == 1) ? 0 : a;

        // --- conv partials by owner waves, from registers, into [e][lane] LDS ---
        #pragma unroll
        for (int k = 0; k < 4; k++) {
            const int s = bankSlot[wid * 4 + k];           // own entry, wave-uniform
            if (s == sa || s == sb) {
                float hl = __shfl_up(R[k][15], 1);  if (lane == 0)  hl = 0.0f;
                float hr = __shfl_down(R[k][0], 1); if (lane == 63) hr = 0.0f;
                float* dst = (s == sa) ? mA : mB;
                const float c0 = (s == sa) ? w00 : w10;
                const float c1 = (s == sa) ? w01 : w11;
                const float c2 = (s == sa) ? w02 : w12;
                #pragma unroll
                for (int e = 0; e < 16; e++) {
                    float xm1 = (e == 0)  ? hl : R[k][e - 1];
                    float xp1 = (e == 15) ? hr : R[k][e + 1];
                    dst[e * 64 + lane] = c0 * xm1 + c1 * R[k][e] + c2 * xp1;
                }
            }
        }
        // --- bookkeeping into NEXT buffers (old buffers stay read-only) ---
        if (tid == 0) nidx[0] = sb;
        if (tid >= 1 && tid < n - 1) {
            int kk = tid + 1;
            int src = (kk == bbj) ? 1 : ((kk == a) ? 0 : kk);
            nidx[tid] = idx[src];
        }
        if (tid < NROWS) npos[tid] = mapPos(pos[tid], n, a, bbj, deadPos);

        // --- scan OLD surviving pairs in NEXT-step numbering -> partial 0..7 ---
        {
            double obk = 1e300; int obp = 0x7fffffff;
            #pragma unroll
            for (int r = 0; r < 2; r++) {
                const int flat = r * BDIM + tid;
                const int s = flat >> 5, t = flat & 31;
                const int js = pos[s], jt = pos[t];        // old buffer, read-only
                const int is2 = mapPos(js, n, a, bbj, deadPos);
                const int jt2 = mapPos(jt, n, a, bbj, deadPos);
                // alive next step AND not the merged row (is2/jt2 >= 1)
                if (t > s && is2 >= 1 && is2 < 127 && jt2 >= 1 && jt2 < 127) {
                    double d2 = D[s][t];
                    int i2 = (is2 < jt2) ? is2 : jt2;
                    int j2 = (is2 < jt2) ? jt2 : is2;
                    int fi = i2 * n1 + j2;
                    if (d2 < obk || (d2 == obk && fi < obp)) { obk = d2; obp = fi; }
                }
            }
            #pragma unroll
            for (int off = 1; off < 64; off <<= 1) {
                double ov = __shfl_xor(obk, off); int op = __shfl_xor(obp, off);
                if (ov < obk || (ov == obk && op < obp)) { obk = ov; obp = op; }
            }
            if (lane == 0) { wpK[p ^ 1][wid] = obk; wpP[p ^ 1][wid] = obp; }
        }
        __syncthreads();                                   // B2

        // ===================== Phase B =====================
        // --- finalize m (all waves need it); conflict-free strided reads ---
        #pragma unroll
        for (int e = 0; e < 16; e++) {
            float v = cb + mA[e * 64 + lane] + mB[e * 64 + lane];
            m[e] = v > 0.0f ? v : 0.0f;
        }
        // owner(sb): bank <- m; owner(deadSlot): kill bank; dists vs live banks
        double accv[4]; int slv[4];
        #pragma unroll
        for (int k = 0; k < 4; k++) {
            int s = bankSlot[wid * 4 + k];
            if (s == sb) {                                 // wave-uniform
                #pragma unroll
                for (int e = 0; e < 16; e++) R[k][e] = m[e];
            }
            if (s == deadSlot) {
                if (lane == 0) bankSlot[wid * 4 + k] = -1;
                s = -1;
            }
            const int live = (s >= 0 && s != sb) ? s : -1;
            slv[k] = live;
            double acc = 0.0;
            if (live >= 0) {                               // wave-uniform
                #pragma unroll
                for (int e = 0; e < 16; e++) {
                    float d = m[e] - R[k][e];
                    acc += (double)d * (double)d;
                }
            }
            accv[k] = acc;
        }
        // joint reduce: lane l holds sum for bank (l&3)
        double c = reduce4(accv[0], accv[1], accv[2], accv[3], lane);
        int s_lane = slv[0];
        s_lane = ((lane & 3) == 1) ? slv[1] : s_lane;
        s_lane = ((lane & 3) == 2) ? slv[2] : s_lane;
        s_lane = ((lane & 3) == 3) ? slv[3] : s_lane;

        double nbk = 1e300; int nbp = 0x7fffffff;
        if (lane < 4 && s_lane >= 0) {
            D[sb][s_lane] = c; D[s_lane][sb] = c;
            // new pair (merged@0, u@j'): flat' = j' (< n' <= any old flat')
            nbk = c;
            nbp = mapPos(pos[s_lane], n, a, bbj, deadPos); // >= 1, alive
        }
        // min across lanes 0..3
        #pragma unroll
        for (int off = 1; off < 4; off <<= 1) {
            double ov = __shfl_xor(nbk, off); int op = __shfl_xor(nbp, off);
            if (ov < nbk || (ov == nbk && op < nbp)) { nbk = ov; nbp = op; }
        }
        if (lane == 0) { wpK[p ^ 1][8 + wid] = nbk; wpP[p ^ 1][8 + wid] = nbp; }
        __syncthreads();                                   // B3
        p ^= 1;
    }

    // final merged row is in m (all waves); wave 0 writes it
    if (wid == 0) {
        float4* od = (float4*)(out + (size_t)b * CDIM);
        #pragma unroll
        for (int q = 0; q < 4; q++)
            od[lane * 4 + q] = make_float4(m[4*q], m[4*q+1], m[4*q+2], m[4*q+3]);
    }
}

extern "C" void kernel_launch(void* const* d_in, const int* in_sizes, int n_in,
                              void* d_out, int out_size, void* d_ws, size_t ws_size,
                              hipStream_t stream) {
    const float* x  = (const float*)d_in[0]; // fp32 (512,32,1024)
    const float* w  = (const float*)d_in[1]; // fp32 (1,2,3)
    const float* cb = (const float*)d_in[2]; // fp32 (1,)
    float* out = (float*)d_out;              // fp32 (512,1024)
    (void)d_ws; (void)ws_size; (void)in_sizes; (void)n_in; (void)out_size;

    hipLaunchKernelGGL(merge_tree_kernel, dim3(BATCH), dim3(BDIM), 0, stream,
                       x, w, cb, out);
}

// Round 4
// 225.114 us; speedup vs baseline: 1.3792x; 1.3792x over previous
//
#include <hip/hip_runtime.h>
#include <stdint.h>

#define BDIM    512                   // 8 waves per batch
#define NROWS   32
#define CDIM    1024
#define NSTEPS  31
#define BATCH   512

// One 512-thread block (8 waves) per batch. ALL alive rows live in REGISTERS:
// wave w owns 4 "banks" k=0..3 holding slots s = w + 8k (strided ownership,
// balanced init); lane holds elements [lane*16..+15]. Merged row overwrites
// slot sb's bank and D-row. The OTHER dead slot is idx[a] normally but
// idx[0] when a==1 (reference quirk) — kill THAT bank.
//
// ALL distance math in fp32 (reference's own d2 is fp32 with ~1e-3 rel
// cancellation noise; fp64 version passed => margins >> our ~2e-6 fp32
// diff-square error => identical decisions => identical output).
// Argmin key is a single u64: (float_bits(d2) << 10) | flat  — float bits
// are order-monotone for d2 >= 0, flat < 1024; u64 min == reference
// (d2, flat) lexicographic order. Branch-free compares everywhere.
// 3 barriers/step. No global reads after init.
__device__ __forceinline__ float reduce4f(float a0, float a1, float a2, float a3, int lane) {
    // Joint wave-sum of 4 fp32 values; lane l ends holding S_{l&3}.
    float t, r, b01, b23, c;
    t = (lane & 1) ? a0 : a1; r = (lane & 1) ? a1 : a0; b01 = r + __shfl_xor(t, 1);
    t = (lane & 1) ? a2 : a3; r = (lane & 1) ? a3 : a2; b23 = r + __shfl_xor(t, 1);
    t = (lane & 2) ? b01 : b23; r = (lane & 2) ? b23 : b01; c = r + __shfl_xor(t, 2);
    c += __shfl_xor(c, 4); c += __shfl_xor(c, 8); c += __shfl_xor(c, 16); c += __shfl_xor(c, 32);
    return c;
}

__global__ __launch_bounds__(BDIM, 4)
void merge_tree_kernel(const float* __restrict__ xin,  // B*32*1024 fp32
                       const float* __restrict__ wz,   // 6 fp32 (1,2,3)
                       const float* __restrict__ bz,   // 1 fp32
                       float* __restrict__ out)        // B*1024 fp32
{
    const int b    = blockIdx.x;
    const int tid  = threadIdx.x;
    const int lane = tid & 63;
    const int wid  = tid >> 6;        // 0..7

    const float* xb = xin + (size_t)b * NROWS * CDIM;

    __shared__ float  D[NROWS][NROWS + 1];   // slot-indexed d2, fp32, padded
    __shared__ float  mA[16 * 64];           // conv partial (ch0), [e][lane]
    __shared__ float  mB[16 * 64];           // conv partial (ch1), [e][lane]
    __shared__ int    idxbuf[2][NROWS];      // logical pos -> slot
    __shared__ int    posb[NROWS];           // slot -> logical pos, 127 = dead
    __shared__ int    bankSlot[32];          // bank (wid*4+k) -> slot, -1 dead
    __shared__ unsigned long long wp[8];     // per-wave argmin partial key

    const float w00 = wz[0], w01 = wz[1], w02 = wz[2];
    const float w10 = wz[3], w11 = wz[4], w12 = wz[5];
    const float cb  = bz[0];

    float R[4][16];                   // 4 owned rows (64 VGPRs)
    float m[16];                      // streamed / merged row
    float nxt[16];                    // init prefetch buffer

    if (tid < NROWS) {
        idxbuf[0][tid] = tid;
        posb[tid] = tid;
        bankSlot[tid] = (tid >> 2) + ((tid & 3) << 3);   // strided ownership
    }

    // ---------- single-pass init: stream row i, owner captures, dist vs s<i ----------
    {
        const float4* src = (const float4*)xb;    // row 0
        #pragma unroll
        for (int q = 0; q < 4; q++) {
            float4 t = src[lane * 4 + q];
            m[4*q] = t.x; m[4*q+1] = t.y; m[4*q+2] = t.z; m[4*q+3] = t.w;
        }
    }
    #pragma unroll 1
    for (int i = 0; i < NROWS; i++) {
        if (i < NROWS - 1) {                      // prefetch row i+1
            const float4* src = (const float4*)(xb + (size_t)(i + 1) * CDIM);
            #pragma unroll
            for (int q = 0; q < 4; q++) {
                float4 t = src[lane * 4 + q];
                nxt[4*q] = t.x; nxt[4*q+1] = t.y; nxt[4*q+2] = t.z; nxt[4*q+3] = t.w;
            }
        }
        float accv[4];
        #pragma unroll
        for (int k = 0; k < 4; k++) {
            const int s = wid + (k << 3);         // strided slot, wave-uniform
            float acc = 0.0f;
            if (s < i) {                          // wave-uniform
                #pragma unroll
                for (int e = 0; e < 16; e++) {
                    float d = m[e] - R[k][e];
                    acc += d * d;
                }
            } else if (s == i) {                  // owner captures streamed row
                #pragma unroll
                for (int e = 0; e < 16; e++) R[k][e] = m[e];
            }
            accv[k] = acc;
        }
        float c = reduce4f(accv[0], accv[1], accv[2], accv[3], lane);
        int s_lane = wid + ((lane & 3) << 3);     // slot for this lane's sum
        if (lane < 4 && s_lane < i) { D[i][s_lane] = c; D[s_lane][i] = c; }

        if (i < NROWS - 1) {
            #pragma unroll
            for (int e = 0; e < 16; e++) m[e] = nxt[e];
        }
    }
    __syncthreads();

    // ---------- main merge loop: 3 barriers/step ----------
    int p = 0;
    #pragma unroll 1
    for (int step = 0; step < NSTEPS; step++) {
        const int n = NROWS - step;
        int* idx  = idxbuf[p];
        int* nidx = idxbuf[p ^ 1];
        const uint32_t M = 0xFFFFFFFFu / (uint32_t)n + 1u;  // exact for flat<2^27

        // --- parallel argmin over slot pairs, ALL 512 threads, u64 keys ---
        unsigned long long bk = ~0ull;
        #pragma unroll
        for (int r = 0; r < (NROWS * NROWS) / BDIM; r++) {  // 2 iterations
            const int flat = r * BDIM + tid;
            const int s = flat >> 5, t = flat & 31;
            const int li = posb[s], lj = posb[t];           // independent LDS loads
            if (t > s && li < n && lj < n) {                // live pair, once
                uint32_t d2b = __float_as_uint(D[s][t]);    // d2 >= 0: monotone bits
                int i2 = (li < lj) ? li : lj;
                int j2 = (li < lj) ? lj : li;
                unsigned long long key =
                    ((unsigned long long)d2b << 10) | (unsigned)(i2 * n + j2);
                bk = (key < bk) ? key : bk;
            }
        }
        #pragma unroll
        for (int off = 1; off < 64; off <<= 1) {
            unsigned long long ov = __shfl_xor(bk, off);
            bk = (ov < bk) ? ov : bk;
        }
        if (lane == 0) wp[wid] = bk;
        __syncthreads();                                   // B1

        // --- final reduce of 8 partials, redundant on every thread (uniform) ---
        bk = wp[0];
        #pragma unroll
        for (int w = 1; w < 8; w++) {
            unsigned long long ov = wp[w];
            bk = (ov < bk) ? ov : bk;
        }
        const int bp  = (int)(bk & 1023u);
        const int a   = (int)__umulhi((uint32_t)bp, M);
        const int bbj = bp - a * n;
        const int sa  = idx[a], sb = idx[bbj];
        const int deadSlot = (a == 1) ? idx[0] : sa;

        // --- conv partials by owner waves, from registers, into [e][lane] LDS ---
        #pragma unroll
        for (int k = 0; k < 4; k++) {
            const int s = bankSlot[wid * 4 + k];           // own entry, wave-uniform
            if (s == sa || s == sb) {
                float hl = __shfl_up(R[k][15], 1);  if (lane == 0)  hl = 0.0f;
                float hr = __shfl_down(R[k][0], 1); if (lane == 63) hr = 0.0f;
                float* dst = (s == sa) ? mA : mB;
                const float c0 = (s == sa) ? w00 : w10;
                const float c1 = (s == sa) ? w01 : w11;
                const float c2 = (s == sa) ? w02 : w12;
                #pragma unroll
                for (int e = 0; e < 16; e++) {
                    float xm1 = (e == 0)  ? hl : R[k][e - 1];
                    float xp1 = (e == 15) ? hr : R[k][e + 1];
                    dst[e * 64 + lane] = c0 * xm1 + c1 * R[k][e] + c2 * xp1;
                }
            }
        }
        // --- bookkeeping: next logical order + slot->pos (all distinct slots) ---
        if (tid == 0) { nidx[0] = sb; posb[sb] = 0; posb[deadSlot] = 127; }
        if (tid >= 1 && tid < n - 1) {
            int kk = tid + 1;
            int src = (kk == bbj) ? 1 : ((kk == a) ? 0 : kk);
            int sl2 = idx[src];
            nidx[tid] = sl2;
            posb[sl2] = tid;                               // survivors distinct; no race
        }
        __syncthreads();                                   // B2

        // --- finalize m (all waves need it); conflict-free strided reads ---
        #pragma unroll
        for (int e = 0; e < 16; e++) {
            float v = cb + mA[e * 64 + lane] + mB[e * 64 + lane];
            m[e] = v > 0.0f ? v : 0.0f;
        }
        // owner(sb): bank <- m; owner(deadSlot): kill bank; dists vs live banks
        float accv[4]; int slv[4];
        #pragma unroll
        for (int k = 0; k < 4; k++) {
            int s = bankSlot[wid * 4 + k];
            if (s == sb) {                                 // wave-uniform
                #pragma unroll
                for (int e = 0; e < 16; e++) R[k][e] = m[e];
            }
            if (s == deadSlot) {
                if (lane == 0) bankSlot[wid * 4 + k] = -1;
                s = -1;
            }
            const int live = (s >= 0 && s != sb) ? s : -1;
            slv[k] = live;
            float acc = 0.0f;
            if (live >= 0) {                               // wave-uniform
                #pragma unroll
                for (int e = 0; e < 16; e++) {
                    float d = m[e] - R[k][e];
                    acc += d * d;
                }
            }
            accv[k] = acc;
        }
        // joint reduce: lane l holds sum for bank (l&3)
        float c = reduce4f(accv[0], accv[1], accv[2], accv[3], lane);
        int s_lane = slv[0];
        s_lane = ((lane & 3) == 1) ? slv[1] : s_lane;
        s_lane = ((lane & 3) == 2) ? slv[2] : s_lane;
        s_lane = ((lane & 3) == 3) ? slv[3] : s_lane;
        if (lane < 4 && s_lane >= 0) {
            D[sb][s_lane] = c; D[s_lane][sb] = c;
        }
        __syncthreads();                                   // B3
        p ^= 1;
    }

    // final merged row is in m (all waves); wave 0 writes it
    if (wid == 0) {
        float4* od = (float4*)(out + (size_t)b * CDIM);
        #pragma unroll
        for (int q = 0; q < 4; q++)
            od[lane * 4 + q] = make_float4(m[4*q], m[4*q+1], m[4*q+2], m[4*q+3]);
    }
}

extern "C" void kernel_launch(void* const* d_in, const int* in_sizes, int n_in,
                              void* d_out, int out_size, void* d_ws, size_t ws_size,
                              hipStream_t stream) {
    const float* x  = (const float*)d_in[0]; // fp32 (512,32,1024)
    const float* w  = (const float*)d_in[1]; // fp32 (1,2,3)
    const float* cb = (const float*)d_in[2]; // fp32 (1,)
    float* out = (float*)d_out;              // fp32 (512,1024)
    (void)d_ws; (void)ws_size; (void)in_sizes; (void)n_in; (void)out_size;

    hipLaunchKernelGGL(merge_tree_kernel, dim3(BATCH), dim3(BDIM), 0, stream,
                       x, w, cb, out);
}

// Round 5
// 213.991 us; speedup vs baseline: 1.4509x; 1.0520x over previous
//
#include <hip/hip_runtime.h>
#include <stdint.h>

#define BDIM    512                   // 8 waves per batch
#define NROWS   32
#define CDIM    1024
#define NSTEPS  31
#define BATCH   512

// One 512-thread block (8 waves) per batch. ALL alive rows live in REGISTERS:
// wave w owns 4 "banks" k=0..3 holding slots s = w + 8k (strided ownership,
// balanced init); lane holds elements [lane*16..+15]. Merged row overwrites
// slot sb's bank and D-row. The OTHER dead slot is idx[a] normally but
// idx[0] when a==1 (reference quirk) — kill THAT bank.
//
// ALL distance math in fp32 (reference's own d2 is fp32 with ~1e-3 rel
// cancellation noise; fp64 version passed => margins >> our ~2e-6 fp32
// diff-square error => identical decisions => identical output). Dist
// accumulation split into two 8-chains (perturbation ~1e-7 rel, 10x below
// the already-validated fp32 switch => decisions unchanged).
// Argmin key is a single u64: (float_bits(d2) << 10) | flat  — float bits
// are order-monotone for d2 >= 0, flat < 1024; u64 min == reference
// (d2, flat) lexicographic order. Branch-free compares everywhere.
//
// conv partials are LANE-ALIGNED (writer lane l produces exactly reader
// lane l's 16 elements) => float4-packed LDS [q][lane]: 4x ds_read_b128
// replaces 16x ds_read_b32 per array; conflict-free both directions.
// 3 barriers/step. No global reads after init.
__device__ __forceinline__ float reduce4f(float a0, float a1, float a2, float a3, int lane) {
    // Joint wave-sum of 4 fp32 values; lane l ends holding S_{l&3}.
    float t, r, b01, b23, c;
    t = (lane & 1) ? a0 : a1; r = (lane & 1) ? a1 : a0; b01 = r + __shfl_xor(t, 1);
    t = (lane & 1) ? a2 : a3; r = (lane & 1) ? a3 : a2; b23 = r + __shfl_xor(t, 1);
    t = (lane & 2) ? b01 : b23; r = (lane & 2) ? b23 : b01; c = r + __shfl_xor(t, 2);
    c += __shfl_xor(c, 4); c += __shfl_xor(c, 8); c += __shfl_xor(c, 16); c += __shfl_xor(c, 32);
    return c;
}

__global__ __launch_bounds__(BDIM, 4)
void merge_tree_kernel(const float* __restrict__ xin,  // B*32*1024 fp32
                       const float* __restrict__ wz,   // 6 fp32 (1,2,3)
                       const float* __restrict__ bz,   // 1 fp32
                       float* __restrict__ out)        // B*1024 fp32
{
    const int b    = blockIdx.x;
    const int tid  = threadIdx.x;
    const int lane = tid & 63;
    const int wid  = tid >> 6;        // 0..7

    const float* xb = xin + (size_t)b * NROWS * CDIM;

    __shared__ float  D[NROWS][NROWS + 1];   // slot-indexed d2, fp32, padded
    __shared__ float4 mA4[4 * 64];           // conv partial (ch0), [q][lane] float4
    __shared__ float4 mB4[4 * 64];           // conv partial (ch1), [q][lane] float4
    __shared__ int    idxbuf[2][NROWS];      // logical pos -> slot
    __shared__ int    posb[NROWS];           // slot -> logical pos, 127 = dead
    __shared__ int    bankSlot[32];          // bank (wid*4+k) -> slot, -1 dead
    __shared__ unsigned long long wp[8];     // per-wave argmin partial key

    const float w00 = wz[0], w01 = wz[1], w02 = wz[2];
    const float w10 = wz[3], w11 = wz[4], w12 = wz[5];
    const float cb  = bz[0];

    float R[4][16];                   // 4 owned rows (64 VGPRs)
    float m[16];                      // streamed / merged row
    float nxt[16];                    // init prefetch buffer

    if (tid < NROWS) {
        idxbuf[0][tid] = tid;
        posb[tid] = tid;
        bankSlot[tid] = (tid >> 2) + ((tid & 3) << 3);   // strided ownership
    }

    // ---------- single-pass init: stream row i, owner captures, dist vs s<i ----------
    {
        const float4* src = (const float4*)xb;    // row 0
        #pragma unroll
        for (int q = 0; q < 4; q++) {
            float4 t = src[lane * 4 + q];
            m[4*q] = t.x; m[4*q+1] = t.y; m[4*q+2] = t.z; m[4*q+3] = t.w;
        }
    }
    #pragma unroll 1
    for (int i = 0; i < NROWS; i++) {
        if (i < NROWS - 1) {                      // prefetch row i+1
            const float4* src = (const float4*)(xb + (size_t)(i + 1) * CDIM);
            #pragma unroll
            for (int q = 0; q < 4; q++) {
                float4 t = src[lane * 4 + q];
                nxt[4*q] = t.x; nxt[4*q+1] = t.y; nxt[4*q+2] = t.z; nxt[4*q+3] = t.w;
            }
        }
        float accv[4];
        #pragma unroll
        for (int k = 0; k < 4; k++) {
            const int s = wid + (k << 3);         // strided slot, wave-uniform
            float acc0 = 0.0f, acc1 = 0.0f;
            if (s < i) {                          // wave-uniform
                #pragma unroll
                for (int e = 0; e < 8; e++) {
                    float d0 = m[e] - R[k][e];
                    float d1 = m[e + 8] - R[k][e + 8];
                    acc0 += d0 * d0;
                    acc1 += d1 * d1;
                }
            } else if (s == i) {                  // owner captures streamed row
                #pragma unroll
                for (int e = 0; e < 16; e++) R[k][e] = m[e];
            }
            accv[k] = acc0 + acc1;
        }
        float c = reduce4f(accv[0], accv[1], accv[2], accv[3], lane);
        int s_lane = wid + ((lane & 3) << 3);     // slot for this lane's sum
        if (lane < 4 && s_lane < i) { D[i][s_lane] = c; D[s_lane][i] = c; }

        if (i < NROWS - 1) {
            #pragma unroll
            for (int e = 0; e < 16; e++) m[e] = nxt[e];
        }
    }
    __syncthreads();

    // ---------- main merge loop: 3 barriers/step ----------
    int p = 0;
    #pragma unroll 1
    for (int step = 0; step < NSTEPS; step++) {
        const int n = NROWS - step;
        int* idx  = idxbuf[p];
        int* nidx = idxbuf[p ^ 1];
        const uint32_t M = 0xFFFFFFFFu / (uint32_t)n + 1u;  // exact for flat<2^27

        // --- parallel argmin over slot pairs, ALL 512 threads, u64 keys ---
        unsigned long long bk = ~0ull;
        #pragma unroll
        for (int r = 0; r < (NROWS * NROWS) / BDIM; r++) {  // 2 iterations
            const int flat = r * BDIM + tid;
            const int s = flat >> 5, t = flat & 31;
            const int li = posb[s], lj = posb[t];           // independent LDS loads
            if (t > s && li < n && lj < n) {                // live pair, once
                uint32_t d2b = __float_as_uint(D[s][t]);    // d2 >= 0: monotone bits
                int i2 = (li < lj) ? li : lj;
                int j2 = (li < lj) ? lj : li;
                unsigned long long key =
                    ((unsigned long long)d2b << 10) | (unsigned)(i2 * n + j2);
                bk = (key < bk) ? key : bk;
            }
        }
        #pragma unroll
        for (int off = 1; off < 64; off <<= 1) {
            unsigned long long ov = __shfl_xor(bk, off);
            bk = (ov < bk) ? ov : bk;
        }
        if (lane == 0) wp[wid] = bk;
        __syncthreads();                                   // B1

        // --- final reduce of 8 partials, redundant on every thread (uniform) ---
        bk = wp[0];
        #pragma unroll
        for (int w = 1; w < 8; w++) {
            unsigned long long ov = wp[w];
            bk = (ov < bk) ? ov : bk;
        }
        const int bp  = (int)(bk & 1023u);
        const int a   = (int)__umulhi((uint32_t)bp, M);
        const int bbj = bp - a * n;
        const int sa  = idx[a], sb = idx[bbj];
        const int deadSlot = (a == 1) ? idx[0] : sa;

        // --- conv partials by owner waves, from registers, float4-packed LDS ---
        #pragma unroll
        for (int k = 0; k < 4; k++) {
            const int s = bankSlot[wid * 4 + k];           // own entry, wave-uniform
            if (s == sa || s == sb) {
                float hl = __shfl_up(R[k][15], 1);  if (lane == 0)  hl = 0.0f;
                float hr = __shfl_down(R[k][0], 1); if (lane == 63) hr = 0.0f;
                float4* dst = (s == sa) ? mA4 : mB4;
                const float c0 = (s == sa) ? w00 : w10;
                const float c1 = (s == sa) ? w01 : w11;
                const float c2 = (s == sa) ? w02 : w12;
                #pragma unroll
                for (int q = 0; q < 4; q++) {
                    float vv[4];
                    #pragma unroll
                    for (int j = 0; j < 4; j++) {
                        const int e = 4 * q + j;
                        float xm1 = (e == 0)  ? hl : R[k][e - 1];
                        float xp1 = (e == 15) ? hr : R[k][e + 1];
                        vv[j] = c0 * xm1 + c1 * R[k][e] + c2 * xp1;
                    }
                    dst[q * 64 + lane] = make_float4(vv[0], vv[1], vv[2], vv[3]);
                }
            }
        }
        // --- bookkeeping: next logical order + slot->pos (all distinct slots) ---
        if (tid == 0) { nidx[0] = sb; posb[sb] = 0; posb[deadSlot] = 127; }
        if (tid >= 1 && tid < n - 1) {
            int kk = tid + 1;
            int src = (kk == bbj) ? 1 : ((kk == a) ? 0 : kk);
            int sl2 = idx[src];
            nidx[tid] = sl2;
            posb[sl2] = tid;                               // survivors distinct; no race
        }
        __syncthreads();                                   // B2

        // --- finalize m: 4x ds_read_b128 per array, conflict-free ---
        #pragma unroll
        for (int q = 0; q < 4; q++) {
            float4 va = mA4[q * 64 + lane];
            float4 vb = mB4[q * 64 + lane];
            float v0 = cb + va.x + vb.x;
            float v1 = cb + va.y + vb.y;
            float v2 = cb + va.z + vb.z;
            float v3 = cb + va.w + vb.w;
            m[4*q+0] = v0 > 0.0f ? v0 : 0.0f;
            m[4*q+1] = v1 > 0.0f ? v1 : 0.0f;
            m[4*q+2] = v2 > 0.0f ? v2 : 0.0f;
            m[4*q+3] = v3 > 0.0f ? v3 : 0.0f;
        }
        // owner(sb): bank <- m; owner(deadSlot): kill bank; dists vs live banks
        float accv[4]; int slv[4];
        #pragma unroll
        for (int k = 0; k < 4; k++) {
            int s = bankSlot[wid * 4 + k];
            if (s == sb) {                                 // wave-uniform
                #pragma unroll
                for (int e = 0; e < 16; e++) R[k][e] = m[e];
            }
            if (s == deadSlot) {
                if (lane == 0) bankSlot[wid * 4 + k] = -1;
                s = -1;
            }
            const int live = (s >= 0 && s != sb) ? s : -1;
            slv[k] = live;
            float acc0 = 0.0f, acc1 = 0.0f;
            if (live >= 0) {                               // wave-uniform
                #pragma unroll
                for (int e = 0; e < 8; e++) {
                    float d0 = m[e] - R[k][e];
                    float d1 = m[e + 8] - R[k][e + 8];
                    acc0 += d0 * d0;
                    acc1 += d1 * d1;
                }
            }
            accv[k] = acc0 + acc1;
        }
        // joint reduce: lane l holds sum for bank (l&3)
        float c = reduce4f(accv[0], accv[1], accv[2], accv[3], lane);
        int s_lane = slv[0];
        s_lane = ((lane & 3) == 1) ? slv[1] : s_lane;
        s_lane = ((lane & 3) == 2) ? slv[2] : s_lane;
        s_lane = ((lane & 3) == 3) ? slv[3] : s_lane;
        if (lane < 4 && s_lane >= 0) {
            D[sb][s_lane] = c; D[s_lane][sb] = c;
        }
        __syncthreads();                                   // B3
        p ^= 1;
    }

    // final merged row is in m (all waves); wave 0 writes it
    if (wid == 0) {
        float4* od = (float4*)(out + (size_t)b * CDIM);
        #pragma unroll
        for (int q = 0; q < 4; q++)
            od[lane * 4 + q] = make_float4(m[4*q], m[4*q+1], m[4*q+2], m[4*q+3]);
    }
}

extern "C" void kernel_launch(void* const* d_in, const int* in_sizes, int n_in,
                              void* d_out, int out_size, void* d_ws, size_t ws_size,
                              hipStream_t stream) {
    const float* x  = (const float*)d_in[0]; // fp32 (512,32,1024)
    const float* w  = (const float*)d_in[1]; // fp32 (1,2,3)
    const float* cb = (const float*)d_in[2]; // fp32 (1,)
    float* out = (float*)d_out;              // fp32 (512,1024)
    (void)d_ws; (void)ws_size; (void)in_sizes; (void)n_in; (void)out_size;

    hipLaunchKernelGGL(merge_tree_kernel, dim3(BATCH), dim3(BDIM), 0, stream,
                       x, w, cb, out);
}